// Round 1
// 143.524 us; speedup vs baseline: 1.0067x; 1.0067x over previous
//
#include <hip/hip_runtime.h>

#define NPTS 512
#define BLOCK 256
#define XPS 68   // xp row stride (dwords): mult of 4 (16B rows), mod 32 = 4 staggers banks

#define GLOBAL_AS(p) ((const __attribute__((address_space(1))) void*)(p))
#define LDS_AS(p)    ((__attribute__((address_space(3))) void*)(p))

// ---------------------------------------------------------------------------
// Kernel 1: per-batch weighted moments — R9: NON-TEMPORAL global_load_lds.
//
// R3-R8 evidence: six load structures (VGPR vector loads x5, LDS-DMA x1) all
// cap at 2.76-2.95 TB/s logical read with every pipe <15% busy, while the
// harness's 256 MiB poison FILL runs 6.4+ TB/s WRITE. Reads at half the
// write rate, equal to one stream of the m13 copy (3.15/dir), is NOT a
// normal HBM read ceiling. New hypothesis: every read line ALLOCATES into
// L2+L3; the 256 MiB/iter poison has just cycled the entire Infinity Cache,
// so each allocation forces an eviction -> effective fabric traffic ~2x the
// logical read stream (2 x 2.9 = 5.8 ~ combined ceiling). The write-only
// fill pays no allocation cost, hence 6.4.
//
// Falsification: mark the streaming reads non-temporal (no-allocate).
// CPol on gfx94x/gfx950: SC0=1, NT=2, SC1=16 -> aux=2 on global_load_lds.
// Inputs are read exactly once per iteration, so caching them is worthless
// regardless of outcome.
//   - If alloc/evict is the cap: moments ~40 -> ~22-28 us.
//   - If unchanged: hard ~3 TB/s read ceiling confirmed at 93% -> roofline.
//
// Staging: one block per batch; src(6 KB)+tgt(6 KB)+w(2 KB) = 14 chunks of
// 1 KB; wave w issues chunks c = w, w+4, ... Each instr: per-lane global
// addr (base + c*1024 + lane*16), wave-uniform LDS dest (smem + c*1024) --
// HW writes lane L at dest + 16L (contiguous, matches layout).
// Accumulate: thread t handles points t, t+256 (stride-3 LDS reads = 2-way
// bank aliasing = free). Reduce: per-wave transpose into xp[16][68] (overlaid
// on the staging buffer after a barrier), quarter-sums via 4x ds_read_b128,
// 2x shfl_xor, cross-wave combine.
// ---------------------------------------------------------------------------
__global__ __launch_bounds__(BLOCK) void wproc_moments(
    const float* __restrict__ src,
    const float* __restrict__ tgt,
    const float* __restrict__ wts,
    float* __restrict__ ws)
{
    const int b = blockIdx.x;
    const int t = threadIdx.x;
    const int wave = t >> 6, lane = t & 63;

    // phase 1: 14336 B staging buffer; phase 2: xp[4][16][68] = 17408 B
    __shared__ __align__(16) char smem[4 * 16 * XPS * 4];
    __shared__ float red[4][16];

    const char* sb = (const char*)(src + (size_t)b * (NPTS * 3));
    const char* tb = (const char*)(tgt + (size_t)b * (NPTS * 3));
    const char* wb = (const char*)(wts + (size_t)b * NPTS);

    // ---- direct-to-LDS staging: 14 x 1KB chunks round-robined over waves ----
    // aux=2: CPol NT (non-temporal, no L2/L3 allocate) — R9 experiment.
    for (int c = wave; c < 14; c += 4) {
        const char* g;
        if (c < 6)       g = sb + (size_t)c * 1024;
        else if (c < 12) g = tb + (size_t)(c - 6) * 1024;
        else             g = wb + (size_t)(c - 12) * 1024;
        __builtin_amdgcn_global_load_lds(
            GLOBAL_AS(g + lane * 16),
            LDS_AS(smem + c * 1024),
            16, 0, 2);
    }
    __syncthreads();   // compiler drains vmcnt before the barrier

    const float* s_s = (const float*)smem;            // [0, 6144)
    const float* s_t = (const float*)(smem + 6144);   // [6144, 12288)
    const float* s_w = (const float*)(smem + 12288);  // [12288, 14336)

    // ---- accumulate 16 moments over 2 points ----
    // [W, m_s(3), m_t(3), M(9) row-major M_ij = sum w*src_i*tgt_j]
    float acc[16];
    #pragma unroll
    for (int i = 0; i < 16; ++i) acc[i] = 0.f;

    #pragma unroll
    for (int k = 0; k < 2; ++k) {
        const int p = t + k * 256;
        float w = s_w[p];
        w = (w < 0.f) ? 0.f : w;  // WEIGHT_THRESHOLD = 0.0
        const float sx = s_s[3 * p + 0], sy = s_s[3 * p + 1], sz = s_s[3 * p + 2];
        const float tx = s_t[3 * p + 0], ty = s_t[3 * p + 1], tz = s_t[3 * p + 2];
        acc[0] += w;
        acc[1] += w * sx; acc[2] += w * sy; acc[3] += w * sz;
        acc[4] += w * tx; acc[5] += w * ty; acc[6] += w * tz;
        const float wsx = w * sx, wsy = w * sy, wsz = w * sz;
        acc[7]  += wsx * tx; acc[8]  += wsx * ty; acc[9]  += wsx * tz;
        acc[10] += wsy * tx; acc[11] += wsy * ty; acc[12] += wsy * tz;
        acc[13] += wsz * tx; acc[14] += wsz * ty; acc[15] += wsz * tz;
    }
    __syncthreads();   // all point reads done before xp overlays the buffer

    float (*xp)[16][XPS] = (float (*)[16][XPS])smem;
    #pragma unroll
    for (int m = 0; m < 16; ++m) xp[wave][m][lane] = acc[m];

    // wave-private: lane m+16q sums quarter q of row m (in-order DS, no barrier)
    {
        const int m = lane & 15, q = lane >> 4;
        const float4* row = (const float4*)&xp[wave][m][0] + 4 * q;
        float4 a0 = row[0], a1 = row[1], a2 = row[2], a3 = row[3];
        a0.x += a1.x; a0.y += a1.y; a0.z += a1.z; a0.w += a1.w;
        a2.x += a3.x; a2.y += a3.y; a2.z += a3.z; a2.w += a3.w;
        a0.x += a2.x; a0.y += a2.y; a0.z += a2.z; a0.w += a2.w;
        float v = (a0.x + a0.y) + (a0.z + a0.w);
        v += __shfl_xor(v, 16, 64);
        v += __shfl_xor(v, 32, 64);
        if (q == 0) red[wave][m] = v;
    }
    __syncthreads();

    if (t < 16) {
        ws[(size_t)b * 16 + t] =
            (red[0][t] + red[1][t]) + (red[2][t] + red[3][t]);
    }
}

// ---------------------------------------------------------------------------
// Kernel 2: per-batch 3x3 Procrustes solve, one lane per batch — 128 dense
// f64 chains total (R6 proved per-wave fusion inflates this 64x; keep split).
//
// Algebra: with T = sum(w)+eps:
//   H = M/T - (2 - W/T) * (m_s/T)(m_t/T)^T   (exact expansion of centered cov)
// SVD-free rotation: Jacobi eigendecomp of A = H^T H -> V; v3 := v1 x v2,
// u_i = H v_i (Gram-Schmidt), u3 := u1 x u2; R = V U^T. Cross products force
// det(U)=det(V)=+1 == reference's diag(1,1,sign(det)) reflection fix.
// ---------------------------------------------------------------------------
__global__ __launch_bounds__(BLOCK) void wproc_solve(
    const float* __restrict__ ws,
    float* __restrict__ out,
    int B)
{
    const int b = blockIdx.x * BLOCK + threadIdx.x;
    if (b >= B) return;

    double m[16];
    #pragma unroll
    for (int i = 0; i < 16; ++i) m[i] = (double)ws[(size_t)b * 16 + i];

    const double T = m[0] + 1e-5;       // sum(w) + EPS
    const double f = 2.0 - m[0] / T;
    const double cs[3] = { m[1] / T, m[2] / T, m[3] / T };
    const double ct[3] = { m[4] / T, m[5] / T, m[6] / T };
    double H[3][3];
    for (int i = 0; i < 3; ++i)
        for (int j = 0; j < 3; ++j)
            H[i][j] = m[7 + i * 3 + j] / T - f * cs[i] * ct[j];

    // A = H^T H (symmetric PSD)
    double A[3][3];
    for (int i = 0; i < 3; ++i)
        for (int j = 0; j < 3; ++j)
            A[i][j] = H[0][i] * H[0][j] + H[1][i] * H[1][j] + H[2][i] * H[2][j];

    // Jacobi eigendecomposition: A = V diag V^T
    double V[3][3] = { {1, 0, 0}, {0, 1, 0}, {0, 0, 1} };
    for (int sweep = 0; sweep < 5; ++sweep) {
        for (int pair = 0; pair < 3; ++pair) {
            const int p = (pair == 2) ? 1 : 0;
            const int q = (pair == 0) ? 1 : 2;
            const double apq = A[p][q];
            if (apq == 0.0) continue;
            const double theta = (A[q][q] - A[p][p]) / (2.0 * apq);
            const double tt = ((theta >= 0.0) ? 1.0 : -1.0)
                            / (fabs(theta) + sqrt(theta * theta + 1.0));
            const double c = 1.0 / sqrt(tt * tt + 1.0);
            const double sn = tt * c;
            for (int k = 0; k < 3; ++k) {  // A <- A G
                const double akp = A[k][p], akq = A[k][q];
                A[k][p] = c * akp - sn * akq;
                A[k][q] = sn * akp + c * akq;
            }
            for (int k = 0; k < 3; ++k) {  // A <- G^T A
                const double apk = A[p][k], aqk = A[q][k];
                A[p][k] = c * apk - sn * aqk;
                A[q][k] = sn * apk + c * aqk;
            }
            for (int k = 0; k < 3; ++k) {  // V <- V G
                const double vkp = V[k][p], vkq = V[k][q];
                V[k][p] = c * vkp - sn * vkq;
                V[k][q] = sn * vkp + c * vkq;
            }
        }
    }

    // sort eigenpairs descending
    const double lam[3] = { A[0][0], A[1][1], A[2][2] };
    int i0 = 0, i1 = 1, i2 = 2;
    if (lam[i0] < lam[i1]) { int tmp = i0; i0 = i1; i1 = tmp; }
    if (lam[i0] < lam[i2]) { int tmp = i0; i0 = i2; i2 = tmp; }
    if (lam[i1] < lam[i2]) { int tmp = i1; i1 = i2; i2 = tmp; }

    const double v1[3] = { V[0][i0], V[1][i0], V[2][i0] };
    const double v2[3] = { V[0][i1], V[1][i1], V[2][i1] };
    const double v3[3] = { v1[1] * v2[2] - v1[2] * v2[1],
                           v1[2] * v2[0] - v1[0] * v2[2],
                           v1[0] * v2[1] - v1[1] * v2[0] };

    double u1[3], u2[3], u3[3];
    for (int i = 0; i < 3; ++i)
        u1[i] = H[i][0] * v1[0] + H[i][1] * v1[1] + H[i][2] * v1[2];
    double n1 = sqrt(u1[0] * u1[0] + u1[1] * u1[1] + u1[2] * u1[2]);
    n1 = (n1 > 1e-30) ? n1 : 1e-30;
    for (int i = 0; i < 3; ++i) u1[i] /= n1;

    for (int i = 0; i < 3; ++i)
        u2[i] = H[i][0] * v2[0] + H[i][1] * v2[1] + H[i][2] * v2[2];
    const double d12 = u1[0] * u2[0] + u1[1] * u2[1] + u1[2] * u2[2];
    for (int i = 0; i < 3; ++i) u2[i] -= d12 * u1[i];
    double n2 = sqrt(u2[0] * u2[0] + u2[1] * u2[1] + u2[2] * u2[2]);
    n2 = (n2 > 1e-30) ? n2 : 1e-30;
    for (int i = 0; i < 3; ++i) u2[i] /= n2;

    u3[0] = u1[1] * u2[2] - u1[2] * u2[1];
    u3[1] = u1[2] * u2[0] - u1[0] * u2[2];
    u3[2] = u1[0] * u2[1] - u1[1] * u2[0];

    double R[3][3];
    for (int i = 0; i < 3; ++i)
        for (int j = 0; j < 3; ++j)
            R[i][j] = v1[i] * u1[j] + v2[i] * u2[j] + v3[i] * u3[j];

    double tv[3];
    for (int i = 0; i < 3; ++i)
        tv[i] = ct[i] - (R[i][0] * cs[0] + R[i][1] * cs[1] + R[i][2] * cs[2]);

    float* outR = out + (size_t)b * 9;
    for (int i = 0; i < 3; ++i)
        for (int j = 0; j < 3; ++j)
            outR[i * 3 + j] = (float)R[i][j];
    float* outT = out + (size_t)B * 9 + (size_t)b * 3;
    for (int i = 0; i < 3; ++i) outT[i] = (float)tv[i];
}

extern "C" void kernel_launch(void* const* d_in, const int* in_sizes, int n_in,
                              void* d_out, int out_size, void* d_ws, size_t ws_size,
                              hipStream_t stream) {
    const float* src = (const float*)d_in[0];
    const float* tgt = (const float*)d_in[1];
    const float* wts = (const float*)d_in[2];
    float* out = (float*)d_out;
    float* ws = (float*)d_ws;   // 16 floats per batch = 512 KB
    const int B = out_size / 12;  // 9 (R) + 3 (t) floats per batch; B=8192

    wproc_moments<<<B, BLOCK, 0, stream>>>(src, tgt, wts, ws);
    wproc_solve<<<(B + BLOCK - 1) / BLOCK, BLOCK, 0, stream>>>(ws, out, B);
}